// Round 5
// baseline (588.960 us; speedup 1.0000x reference)
//
#include <hip/hip_runtime.h>
#include <hip/hip_fp16.h>
#include <math.h>

typedef unsigned int uint;
typedef _Float16 f16x8 __attribute__((ext_vector_type(8)));
typedef float f32x4 __attribute__((ext_vector_type(4)));

#define NT 256

// ---------------- ws layout (uint/f32 words) ----------------
// 0     : W_l0 frags   [16 tiles][3 ksteps][64 lanes][4 uint]  = 12288
//         (s=0 also carries fused bias0 at k=16 via constant-1 input)
// 12288 : W_l1 frags   [16][4][64][4]                          = 16384
// 28672 : W_v1 frags   [4][64][4]                              = 1024
// 29696 : W_v2 frags   [2][64][4]                              = 512
// 30208 : b1frag  f32  [4][64][4]                              = 1024
// 31232 : b2frag  f32  [64][4]                                 = 256
// 31488 : bias0frag f32 [16][64][4]  (unused by main now)      = 4096
// 35584 : bias1frag f32 [16][64][4]                            = 4096

// ---------------- LDS layout (bytes) ----------------
// B-operand buffers are fragment-linear: granule g = (k>>3)*16 + batch,
// 16B per granule = halves k&7.  B-frag read address = base + lane*16.
#define O_VW1 0        // 4096  VSN1 A-frags [4 tiles][64 lanes][16B]
#define O_VW2 4096     // 2048  VSN2 A-frags [2][64][16B]
#define O_B1F 6144     // 4096  b1 frag f32x4 [4][64]
#define O_B2F 10240    // 1024  b2 frag f32x4 [64]
#define O_XB  11264    // 1024  x  B-frag (k0..7 = feat, k8 = delta, rest 0)
#define O_XS  12288    // 1024  x~ B-frag (k16 = 1.0 const for bias0)
#define O_HID 13312    // 2048  VSN hidden B-frag (K=64)
#define O_H0  15360    // 2048  h0 B-frag (K=64)
#define O_H1  17408    // 2048  h1 B-frag (K=64)
#define O_WP  19456    // 384   f32 [8 batch][12] delta partials
#define LDS_BYTES 19840

__device__ __forceinline__ float fexp2(float x) { return __builtin_amdgcn_exp2f(x); }
__device__ __forceinline__ float frcp(float x)  { return __builtin_amdgcn_rcpf(x); }
__device__ __forceinline__ float sigm(float x)  { return frcp(1.0f + fexp2(-1.44269504f * x)); }
__device__ __forceinline__ float tanh_(float x) { return fmaf(2.0f, frcp(1.0f + fexp2(-2.88539008f * x)), -1.0f); }

__device__ __forceinline__ uint pack2(float lo, float hi) {
    return ((uint)__half_as_ushort(__float2half_rn(hi)) << 16) |
           (uint)__half_as_ushort(__float2half_rn(lo));
}
__device__ __forceinline__ unsigned short f16b(float x) {
    return __half_as_ushort(__float2half_rn(x));
}
__device__ __forceinline__ f16x8 ldfrag(const uint* p) {
    union { uint4 u; f16x8 h; } c;
    c.u = *(const uint4*)p;
    return c.h;
}
__device__ __forceinline__ float lstm_out(const f32x4 a, float& c) {
    float ii = sigm(a[0]), ff = sigm(a[1]);
    float gg = tanh_(a[2]), oo = sigm(a[3]);
    c = fmaf(ff, c, ii * gg);
    return oo * tanh_(c);
}

// A-frag (16x16x32 f16): lane l holds A[row16 = l&15][k = (l>>4)*8 + e].
// LSTM tiles gate-interleaved: row16 -> R = (row16&3)*64 + 4*tile + (row16>>2).
__global__ __launch_bounds__(1024)
void prep_kernel(const float* __restrict__ W1,  const float* __restrict__ b1,
                 const float* __restrict__ W2,  const float* __restrict__ b2,
                 const float* __restrict__ Wih0, const float* __restrict__ Whh0,
                 const float* __restrict__ bih0, const float* __restrict__ bhh0,
                 const float* __restrict__ Wih1, const float* __restrict__ Whh1,
                 const float* __restrict__ bih1, const float* __restrict__ bhh1,
                 uint* __restrict__ ws)
{
    const int tid = blockIdx.x * 1024 + threadIdx.x;
    float* wsf = (float*)ws;

    if (tid < 12288) {                               // W_l0
        int v = tid & 3, l = (tid >> 2) & 63, ts = tid >> 8;
        int s = ts % 3, w = ts / 3;
        int R = (l & 3) * 64 + 4 * w + ((l >> 2) & 3);
        int k0 = (l >> 4) * 8 + 2 * v;
        float lo = 0.f, hi = 0.f;
        if (s == 0) {
            if (k0     < 9) lo = Wih0[R * 9 + k0];
            if (k0 + 1 < 9) hi = Wih0[R * 9 + k0 + 1];
            if (k0 == 16)   lo = bih0[R] + bhh0[R];   // bias via const-1 at k=16
        } else {
            int kh = 32 * (s - 1) + k0;
            lo = Whh0[R * 64 + kh]; hi = Whh0[R * 64 + kh + 1];
        }
        ws[tid] = pack2(lo, hi);
    } else if (tid < 28672) {                        // W_l1
        int idx = tid - 12288;
        int v = idx & 3, l = (idx >> 2) & 63, ts = idx >> 8;
        int s = ts & 3, w = ts >> 2;
        int R = (l & 3) * 64 + 4 * w + ((l >> 2) & 3);
        int kt = 32 * s + (l >> 4) * 8 + 2 * v;
        float lo, hi;
        if (kt < 64) { lo = Wih1[R * 64 + kt];      hi = Wih1[R * 64 + kt + 1]; }
        else         { lo = Whh1[R * 64 + kt - 64]; hi = Whh1[R * 64 + kt - 63]; }
        ws[tid] = pack2(lo, hi);
    } else if (tid < 29696) {                        // W_v1
        int idx = tid - 28672;
        int v = idx & 3, l = (idx >> 2) & 63, m = idx >> 8;
        int j2 = 16 * m + (l & 15);
        int k0 = (l >> 4) * 8 + 2 * v;
        float lo = (k0     < 9) ? W1[j2 * 9 + k0]     : 0.f;
        float hi = (k0 + 1 < 9) ? W1[j2 * 9 + k0 + 1] : 0.f;
        ws[tid] = pack2(lo, hi);
    } else if (tid < 30208) {                        // W_v2 (rows padded to 16)
        int idx = tid - 29696;
        int v = idx & 3, l = (idx >> 2) & 63, s = idx >> 8;
        int rr = l & 15;
        int k0 = 32 * s + (l >> 4) * 8 + 2 * v;
        float lo = (rr < 9) ? W2[rr * 64 + k0]     : 0.f;
        float hi = (rr < 9) ? W2[rr * 64 + k0 + 1] : 0.f;
        ws[tid] = pack2(lo, hi);
    } else if (tid < 31232) {                        // b1frag
        int idx = tid - 30208;
        int r = idx & 3, l = (idx >> 2) & 63, m = idx >> 8;
        wsf[tid] = b1[16 * m + (l >> 4) * 4 + r];
    } else if (tid < 31488) {                        // b2frag (-1e30 pad rows)
        int idx = tid - 31232;
        int r = idx & 3, l = idx >> 2;
        int row = (l >> 4) * 4 + r;
        wsf[tid] = (row < 9) ? b2[row] : -1e30f;
    } else if (tid < 35584) {                        // bias0frag (legacy, unused)
        int idx = tid - 31488;
        int r = idx & 3, l = (idx >> 2) & 63, w = idx >> 8;
        int R = r * 64 + 4 * w + (l >> 4);
        wsf[tid] = bih0[R] + bhh0[R];
    } else if (tid < 39680) {                        // bias1frag
        int idx = tid - 35584;
        int r = idx & 3, l = (idx >> 2) & 63, w = idx >> 8;
        int R = r * 64 + 4 * w + (l >> 4);
        wsf[tid] = bih1[R] + bhh1[R];
    }
}

// 512 blocks x 512 threads (8 waves). 8 batches/block, 2 blocks/CU.
// Wave w owns gate-row tiles 2w, 2w+1  (hidden j in [8w, 8w+8)).
__global__ __launch_bounds__(512, 4)
void tft_main(const float* __restrict__ feat,
              const float* __restrict__ Wo, const float* __restrict__ bo,
              const uint* __restrict__ ws,
              float* __restrict__ out)
{
    __shared__ unsigned char smem[LDS_BYTES];
    const int tid  = threadIdx.x;
    const int lane = tid & 63;
    const int w    = tid >> 6;        // 0..7
    const int q    = lane >> 4;       // 0..3
    const int cb   = lane & 15;       // batch column (0..7 valid)
    const int b0   = blockIdx.x * 8;
    const int tA   = 2 * w, tB = 2 * w + 1;

    // ---- one-time init: copy VSN block (704 uint4) + zero dynamic area ----
    {
        const uint4* vsrc = (const uint4*)(ws + 28672);
        uint4* dst = (uint4*)smem;
        uint4 z = {0u, 0u, 0u, 0u};
        #pragma unroll
        for (int i = 0; i < 3; ++i) {
            int idx = tid + i * 512;
            if (idx < 704) dst[idx] = vsrc[idx];
            else if (idx < LDS_BYTES / 16) dst[idx] = z;
        }
    }

    // ---- LSTM weights -> registers ----
    const f16x8 wl0_0A = ldfrag(ws + (tA * 3 + 0) * 256 + lane * 4);
    const f16x8 wl0_1A = ldfrag(ws + (tA * 3 + 1) * 256 + lane * 4);
    const f16x8 wl0_2A = ldfrag(ws + (tA * 3 + 2) * 256 + lane * 4);
    const f16x8 wl0_0B = ldfrag(ws + (tB * 3 + 0) * 256 + lane * 4);
    const f16x8 wl0_1B = ldfrag(ws + (tB * 3 + 1) * 256 + lane * 4);
    const f16x8 wl0_2B = ldfrag(ws + (tB * 3 + 2) * 256 + lane * 4);
    const f16x8 wl1_0A = ldfrag(ws + 12288 + (tA * 4 + 0) * 256 + lane * 4);
    const f16x8 wl1_1A = ldfrag(ws + 12288 + (tA * 4 + 1) * 256 + lane * 4);
    const f16x8 wl1_2A = ldfrag(ws + 12288 + (tA * 4 + 2) * 256 + lane * 4);
    const f16x8 wl1_3A = ldfrag(ws + 12288 + (tA * 4 + 3) * 256 + lane * 4);
    const f16x8 wl1_0B = ldfrag(ws + 12288 + (tB * 4 + 0) * 256 + lane * 4);
    const f16x8 wl1_1B = ldfrag(ws + 12288 + (tB * 4 + 1) * 256 + lane * 4);
    const f16x8 wl1_2B = ldfrag(ws + 12288 + (tB * 4 + 2) * 256 + lane * 4);
    const f16x8 wl1_3B = ldfrag(ws + 12288 + (tB * 4 + 3) * 256 + lane * 4);

    const float* wsf = (const float*)ws;
    const float4 bias1A = *(const float4*)(wsf + 35584 + (tA * 64 + lane) * 4);
    const float4 bias1B = *(const float4*)(wsf + 35584 + (tB * 64 + lane) * 4);
    const float wojA = Wo[8 * w + q];
    const float wojB = Wo[8 * w + 4 + q];
    const float bov  = bo[0];

    float c0A = 0.f, c0B = 0.f, c1A = 0.f, c1B = 0.f;
    float4 px = {0.f, 0.f, 0.f, 0.f};
    if (tid < 16) {
        int pb = tid >> 1, ph = tid & 1;
        px = *(const float4*)(feat + ((size_t)(b0 + pb) * NT) * 8 + 4 * ph);
    }
    __syncthreads();
    // constant-1.0 input at k=16 of XS (feeds fused bias0); set once after zeroing
    if (tid < 16) *(unsigned short*)(smem + O_XS + (32 + tid) * 16) = 0x3C00;
    __syncthreads();

    #pragma unroll 1
    for (int t = 0; t < NT; ++t) {
        // ---- P0: finalize delta(t-1), stage x_t (fp16 frag-linear), prefetch ----
        if (tid < 8) {
            float s = bov;
            if (t > 0) {
                const float* wp = (const float*)(smem + O_WP) + tid * 12;
                float4 sa = *(const float4*)(wp);
                float4 sb = *(const float4*)(wp + 4);
                s += sa.x + sa.y + sa.z + sa.w + sb.x + sb.y + sb.z + sb.w;
                out[(size_t)(b0 + tid) * NT + (t - 1)] = s;
            } else s = 0.f;
            *(unsigned short*)(smem + O_XB + (16 + tid) * 16) = f16b(s);   // k=8
        }
        if (tid < 16) {
            int pb = tid >> 1, ph = tid & 1;
            uint2 p2; p2.x = pack2(px.x, px.y); p2.y = pack2(px.z, px.w);
            *(uint2*)(smem + O_XB + pb * 16 + ph * 8) = p2;
            if (t + 1 < NT)
                px = *(const float4*)(feat + ((size_t)(b0 + pb) * NT + (t + 1)) * 8 + 4 * ph);
        }
        __syncthreads();   // A

        // ---- P1: all waves: hoisted recurrent MFMAs; wave 4: full VSN ----
        f32x4 a0A = {0.f, 0.f, 0.f, 0.f};
        f32x4 a0B = {0.f, 0.f, 0.f, 0.f};
        f32x4 a1A = {bias1A.x, bias1A.y, bias1A.z, bias1A.w};
        f32x4 a1B = {bias1B.x, bias1B.y, bias1B.z, bias1B.w};
        {
            f16x8 h0a = *(const f16x8*)(smem + O_H0 + lane * 16);
            f16x8 h0b = *(const f16x8*)(smem + O_H0 + 1024 + lane * 16);
            f16x8 h1a = *(const f16x8*)(smem + O_H1 + lane * 16);
            f16x8 h1b = *(const f16x8*)(smem + O_H1 + 1024 + lane * 16);
            a0A = __builtin_amdgcn_mfma_f32_16x16x32_f16(wl0_1A, h0a, a0A, 0, 0, 0);
            a0B = __builtin_amdgcn_mfma_f32_16x16x32_f16(wl0_1B, h0a, a0B, 0, 0, 0);
            a1A = __builtin_amdgcn_mfma_f32_16x16x32_f16(wl1_2A, h1a, a1A, 0, 0, 0);
            a1B = __builtin_amdgcn_mfma_f32_16x16x32_f16(wl1_2B, h1a, a1B, 0, 0, 0);
            a0A = __builtin_amdgcn_mfma_f32_16x16x32_f16(wl0_2A, h0b, a0A, 0, 0, 0);
            a0B = __builtin_amdgcn_mfma_f32_16x16x32_f16(wl0_2B, h0b, a0B, 0, 0, 0);
            a1A = __builtin_amdgcn_mfma_f32_16x16x32_f16(wl1_3A, h1b, a1A, 0, 0, 0);
            a1B = __builtin_amdgcn_mfma_f32_16x16x32_f16(wl1_3B, h1b, a1B, 0, 0, 0);
        }
        if (w == 4) {
            // VSN1: 4 MFMAs over all 64 hidden rows
            f16x8 xb = *(const f16x8*)(smem + O_XB + lane * 16);
            #pragma unroll
            for (int m = 0; m < 4; ++m) {
                float4 b1f = *(const float4*)(smem + O_B1F + m * 1024 + lane * 16);
                f16x8 wv  = *(const f16x8*)(smem + O_VW1 + m * 1024 + lane * 16);
                f32x4 acc = {b1f.x, b1f.y, b1f.z, b1f.w};
                acc = __builtin_amdgcn_mfma_f32_16x16x32_f16(wv, xb, acc, 0, 0, 0);
                uint2 hw;
                hw.x = pack2(fmaxf(acc[0], 0.f), fmaxf(acc[1], 0.f));
                hw.y = pack2(fmaxf(acc[2], 0.f), fmaxf(acc[3], 0.f));
                *(uint2*)(smem + O_HID + ((2 * m + (q >> 1)) * 16 + cb) * 16 + (q & 1) * 8) = hw;
            }
            // VSN2 + softmax (skip-max; pad rows have b2=-1e30 -> e=0)
            f16x8 hb0  = *(const f16x8*)(smem + O_HID + lane * 16);
            f16x8 hb1  = *(const f16x8*)(smem + O_HID + 1024 + lane * 16);
            float4 b2f = *(const float4*)(smem + O_B2F + lane * 16);
            f16x8 wv20 = *(const f16x8*)(smem + O_VW2 + lane * 16);
            f16x8 wv21 = *(const f16x8*)(smem + O_VW2 + 1024 + lane * 16);
            f32x4 acc = {b2f.x, b2f.y, b2f.z, b2f.w};
            acc = __builtin_amdgcn_mfma_f32_16x16x32_f16(wv20, hb0, acc, 0, 0, 0);
            acc = __builtin_amdgcn_mfma_f32_16x16x32_f16(wv21, hb1, acc, 0, 0, 0);
            float e0 = fexp2(1.44269504f * acc[0]);
            float e1 = fexp2(1.44269504f * acc[1]);
            float e2 = fexp2(1.44269504f * acc[2]);
            float e3 = fexp2(1.44269504f * acc[3]);
            float sm = (e0 + e1) + (e2 + e3);
            sm += __shfl_xor(sm, 16, 64);
            sm += __shfl_xor(sm, 32, 64);
            float inv = frcp(sm);
            const int xoff = ((q >= 2 ? 16 : 0) + cb) * 16 + (q & 1) * 8;
            uint2 xw = *(const uint2*)(smem + O_XB + xoff);
            const __half* xh = (const __half*)&xw;
            float v0 = __half2float(xh[0]) * e0 * inv;
            float v1 = __half2float(xh[1]) * e1 * inv;
            float v2 = __half2float(xh[2]) * e2 * inv;
            float v3 = __half2float(xh[3]) * e3 * inv;
            uint2 xsw; xsw.x = pack2(v0, v1); xsw.y = pack2(v2, v3);
            *(uint2*)(smem + O_XS + xoff) = xsw;
        }
        __syncthreads();   // C

        // ---- P2: LSTM0 finish: 2 MFMAs (shared x~ frag) + gates ----
        {
            f16x8 bx = *(const f16x8*)(smem + O_XS + lane * 16);
            a0A = __builtin_amdgcn_mfma_f32_16x16x32_f16(wl0_0A, bx, a0A, 0, 0, 0);
            a0B = __builtin_amdgcn_mfma_f32_16x16x32_f16(wl0_0B, bx, a0B, 0, 0, 0);
            float hA = lstm_out(a0A, c0A);
            float hB = lstm_out(a0B, c0B);
            *(unsigned short*)(smem + O_H0 + (w * 16 + cb) * 16 + q * 2)     = f16b(hA);
            *(unsigned short*)(smem + O_H0 + (w * 16 + cb) * 16 + 8 + q * 2) = f16b(hB);
        }
        __syncthreads();   // D

        // ---- P3: LSTM1 finish: 4 MFMAs + gates + delta partial ----
        {
            f16x8 h0a = *(const f16x8*)(smem + O_H0 + lane * 16);
            f16x8 h0b = *(const f16x8*)(smem + O_H0 + 1024 + lane * 16);
            a1A = __builtin_amdgcn_mfma_f32_16x16x32_f16(wl1_0A, h0a, a1A, 0, 0, 0);
            a1B = __builtin_amdgcn_mfma_f32_16x16x32_f16(wl1_0B, h0a, a1B, 0, 0, 0);
            a1A = __builtin_amdgcn_mfma_f32_16x16x32_f16(wl1_1A, h0b, a1A, 0, 0, 0);
            a1B = __builtin_amdgcn_mfma_f32_16x16x32_f16(wl1_1B, h0b, a1B, 0, 0, 0);
            float hA = lstm_out(a1A, c1A);
            float hB = lstm_out(a1B, c1B);
            *(unsigned short*)(smem + O_H1 + (w * 16 + cb) * 16 + q * 2)     = f16b(hA);
            *(unsigned short*)(smem + O_H1 + (w * 16 + cb) * 16 + 8 + q * 2) = f16b(hB);
            float p = fmaf(wojA, hA, wojB * hB);
            p += __shfl_xor(p, 16, 64);
            p += __shfl_xor(p, 32, 64);
            if (lane < 8) ((float*)(smem + O_WP))[lane * 12 + w] = p;
        }
        __syncthreads();   // E
    }

    // ---- epilogue: delta for t = 255 ----
    if (tid < 8) {
        const float* wp = (const float*)(smem + O_WP) + tid * 12;
        float4 sa = *(const float4*)(wp);
        float4 sb = *(const float4*)(wp + 4);
        float s = bov + sa.x + sa.y + sa.z + sa.w + sb.x + sb.y + sb.z + sb.w;
        out[(size_t)(b0 + tid) * NT + (NT - 1)] = s;
    }
}

extern "C" void kernel_launch(void* const* d_in, const int* in_sizes, int n_in,
                              void* d_out, int out_size, void* d_ws, size_t ws_size,
                              hipStream_t stream) {
    const float* feat = (const float*)d_in[0];
    const float* W1   = (const float*)d_in[1];
    const float* b1   = (const float*)d_in[2];
    const float* W2   = (const float*)d_in[3];
    const float* b2   = (const float*)d_in[4];
    const float* Wih0 = (const float*)d_in[5];
    const float* Whh0 = (const float*)d_in[6];
    const float* bih0 = (const float*)d_in[7];
    const float* bhh0 = (const float*)d_in[8];
    const float* Wih1 = (const float*)d_in[9];
    const float* Whh1 = (const float*)d_in[10];
    const float* bih1 = (const float*)d_in[11];
    const float* bhh1 = (const float*)d_in[12];
    const float* Wo   = (const float*)d_in[13];
    const float* bo   = (const float*)d_in[14];
    uint* ws   = (uint*)d_ws;
    float* out = (float*)d_out;

    hipLaunchKernelGGL(prep_kernel, dim3(40), dim3(1024), 0, stream,
                       W1, b1, W2, b2, Wih0, Whh0, bih0, bhh0,
                       Wih1, Whh1, bih1, bhh1, ws);
    // 512 blocks x 512 threads: 8 batches/block, 2 blocks per CU
    hipLaunchKernelGGL(tft_main, dim3(512), dim3(512), 0, stream,
                       feat, Wo, bo, ws, out);
}

// Round 6
// 362.511 us; speedup vs baseline: 1.6247x; 1.6247x over previous
//
#include <hip/hip_runtime.h>
#include <hip/hip_fp16.h>
#include <math.h>

typedef unsigned int uint;
typedef _Float16 f16x8 __attribute__((ext_vector_type(8)));
typedef float f32x4 __attribute__((ext_vector_type(4)));

#define NT 256

// ---------------- ws layout (uint/f32 words) ----------------
// 0     : W_l0 frags   [16 tiles][3 ksteps][64 lanes][4 uint]  = 12288
//         (s=0 carries fused bias0 at k=16, fed by const-1 in XS)
// 12288 : W_l1 frags   [16][4][64][4]                          = 16384
// 28672 : W_v1 frags   [4][64][4]                              = 1024
// 29696 : W_v2 frags   [2][64][4]                              = 512
// 30208 : b1frag  f32  [4][64][4]                              = 1024
// 31232 : b2frag  f32  [64][4]  (-1e30 pad rows)               = 256
// 31488 : bias0frag    (legacy, unused)                        = 4096
// 35584 : bias1frag f32 [16][64][4]                            = 4096

// ---------------- LDS layout (bytes), all frag-linear ----------------
// B-operand granule g = (k>>3)*16 + batch, 16B = halves k&7.
// Frag read for K-step s:  base + (s*64 + lane)*16.
#define O_XB  0       // 256   x_t features k0..7   [granule 0..15]
#define O_XS  256     // 1024  x~ (k0..8; k16=1.0 const for bias0)
#define O_HID 1280    // 2048  VSN hidden, K=64
#define O_H0  3328    // 2048  h0, K=64
#define O_H1  5376    // 2048  h1, K=64
#define O_WP  7424    // 1280  f32 [16 batch][20] delta partials
#define LDS_BYTES 8704

__device__ __forceinline__ float fexp2(float x) { return __builtin_amdgcn_exp2f(x); }
__device__ __forceinline__ float frcp(float x)  { return __builtin_amdgcn_rcpf(x); }
__device__ __forceinline__ float sigm(float x)  { return frcp(1.0f + fexp2(-1.44269504f * x)); }
__device__ __forceinline__ float tanh_(float x) { return fmaf(2.0f, frcp(1.0f + fexp2(-2.88539008f * x)), -1.0f); }

__device__ __forceinline__ uint pack2(float lo, float hi) {
    return ((uint)__half_as_ushort(__float2half_rn(hi)) << 16) |
           (uint)__half_as_ushort(__float2half_rn(lo));
}
__device__ __forceinline__ unsigned short f16b(float x) {
    return __half_as_ushort(__float2half_rn(x));
}
__device__ __forceinline__ f16x8 ldfrag(const uint* p) {
    union { uint4 u; f16x8 h; } c;
    c.u = *(const uint4*)p;
    return c.h;
}
__device__ __forceinline__ float lstm_out(const f32x4 a, float& c) {
    float ii = sigm(a[0]), ff = sigm(a[1]);
    float gg = tanh_(a[2]), oo = sigm(a[3]);
    c = fmaf(ff, c, ii * gg);
    return oo * tanh_(c);
}
__device__ __forceinline__ float wp_reduce(const unsigned char* smem, int cb) {
    const float* wp = (const float*)(smem + O_WP) + cb * 20;
    float4 s0 = *(const float4*)(wp);
    float4 s1 = *(const float4*)(wp + 4);
    float4 s2 = *(const float4*)(wp + 8);
    float4 s3 = *(const float4*)(wp + 12);
    return ((s0.x + s0.y) + (s0.z + s0.w)) + ((s1.x + s1.y) + (s1.z + s1.w))
         + ((s2.x + s2.y) + (s2.z + s2.w)) + ((s3.x + s3.y) + (s3.z + s3.w));
}

// A-frag (16x16x32 f16): lane l holds A[row16 = l&15][k = (l>>4)*8 + e].
// LSTM tiles gate-interleaved: row16 -> R = (row16&3)*64 + 4*tile + (row16>>2).
__global__ __launch_bounds__(1024)
void prep_kernel(const float* __restrict__ W1,  const float* __restrict__ b1,
                 const float* __restrict__ W2,  const float* __restrict__ b2,
                 const float* __restrict__ Wih0, const float* __restrict__ Whh0,
                 const float* __restrict__ bih0, const float* __restrict__ bhh0,
                 const float* __restrict__ Wih1, const float* __restrict__ Whh1,
                 const float* __restrict__ bih1, const float* __restrict__ bhh1,
                 uint* __restrict__ ws)
{
    const int tid = blockIdx.x * 1024 + threadIdx.x;
    float* wsf = (float*)ws;

    if (tid < 12288) {                               // W_l0
        int v = tid & 3, l = (tid >> 2) & 63, ts = tid >> 8;
        int s = ts % 3, w = ts / 3;
        int R = (l & 3) * 64 + 4 * w + ((l >> 2) & 3);
        int k0 = (l >> 4) * 8 + 2 * v;
        float lo = 0.f, hi = 0.f;
        if (s == 0) {
            if (k0     < 9) lo = Wih0[R * 9 + k0];
            if (k0 + 1 < 9) hi = Wih0[R * 9 + k0 + 1];
            if (k0 == 16)   lo = bih0[R] + bhh0[R];   // bias via const-1 at k=16
        } else {
            int kh = 32 * (s - 1) + k0;
            lo = Whh0[R * 64 + kh]; hi = Whh0[R * 64 + kh + 1];
        }
        ws[tid] = pack2(lo, hi);
    } else if (tid < 28672) {                        // W_l1
        int idx = tid - 12288;
        int v = idx & 3, l = (idx >> 2) & 63, ts = idx >> 8;
        int s = ts & 3, w = ts >> 2;
        int R = (l & 3) * 64 + 4 * w + ((l >> 2) & 3);
        int kt = 32 * s + (l >> 4) * 8 + 2 * v;
        float lo, hi;
        if (kt < 64) { lo = Wih1[R * 64 + kt];      hi = Wih1[R * 64 + kt + 1]; }
        else         { lo = Whh1[R * 64 + kt - 64]; hi = Whh1[R * 64 + kt - 63]; }
        ws[tid] = pack2(lo, hi);
    } else if (tid < 29696) {                        // W_v1
        int idx = tid - 28672;
        int v = idx & 3, l = (idx >> 2) & 63, m = idx >> 8;
        int j2 = 16 * m + (l & 15);
        int k0 = (l >> 4) * 8 + 2 * v;
        float lo = (k0     < 9) ? W1[j2 * 9 + k0]     : 0.f;
        float hi = (k0 + 1 < 9) ? W1[j2 * 9 + k0 + 1] : 0.f;
        ws[tid] = pack2(lo, hi);
    } else if (tid < 30208) {                        // W_v2 (rows padded to 16)
        int idx = tid - 29696;
        int v = idx & 3, l = (idx >> 2) & 63, s = idx >> 8;
        int rr = l & 15;
        int k0 = 32 * s + (l >> 4) * 8 + 2 * v;
        float lo = (rr < 9) ? W2[rr * 64 + k0]     : 0.f;
        float hi = (rr < 9) ? W2[rr * 64 + k0 + 1] : 0.f;
        ws[tid] = pack2(lo, hi);
    } else if (tid < 31232) {                        // b1frag
        int idx = tid - 30208;
        int r = idx & 3, l = (idx >> 2) & 63, m = idx >> 8;
        wsf[tid] = b1[16 * m + (l >> 4) * 4 + r];
    } else if (tid < 31488) {                        // b2frag (-1e30 pad rows)
        int idx = tid - 31232;
        int r = idx & 3, l = idx >> 2;
        int row = (l >> 4) * 4 + r;
        wsf[tid] = (row < 9) ? b2[row] : -1e30f;
    } else if (tid < 35584) {                        // bias0frag (legacy, unused)
        int idx = tid - 31488;
        int r = idx & 3, l = (idx >> 2) & 63, w = idx >> 8;
        int R = r * 64 + 4 * w + (l >> 4);
        wsf[tid] = bih0[R] + bhh0[R];
    } else if (tid < 39680) {                        // bias1frag
        int idx = tid - 35584;
        int r = idx & 3, l = (idx >> 2) & 63, w = idx >> 8;
        int R = r * 64 + 4 * w + (l >> 4);
        wsf[tid] = bih1[R] + bhh1[R];
    }
}

// 256 blocks x 1024 threads (16 waves), 16 batches/block, 1 block/CU.
// Wave w owns hidden j in [4w, 4w+4); lane (q,cb): j = 4w+q, batch cb,
// acc regs = gates {i,f,g,o} (gate-interleaved A rows).
__global__ __launch_bounds__(1024)
void tft_main(const float* __restrict__ feat,
              const float* __restrict__ Wo, const float* __restrict__ bo,
              const uint* __restrict__ ws,
              float* __restrict__ out)
{
    __shared__ unsigned char smem[LDS_BYTES];
    const int tid  = threadIdx.x;
    const int lane = tid & 63;
    const int w    = tid >> 6;        // 0..15
    const int q    = lane >> 4;       // 0..3
    const int cb   = lane & 15;       // batch column
    const int b0   = blockIdx.x * 16;

    // ---- zero LDS ----
    {
        uint4 z = {0u, 0u, 0u, 0u};
        if (tid < LDS_BYTES / 16) ((uint4*)smem)[tid] = z;
    }

    // ---- weights -> registers ----
    const f16x8 wl0_0 = ldfrag(ws + (w * 3 + 0) * 256 + lane * 4);   // x~ + bias0
    const f16x8 wl0_1 = ldfrag(ws + (w * 3 + 1) * 256 + lane * 4);   // Whh0 K0..31
    const f16x8 wl0_2 = ldfrag(ws + (w * 3 + 2) * 256 + lane * 4);   // Whh0 K32..63
    const f16x8 wl1_0 = ldfrag(ws + 12288 + (w * 4 + 0) * 256 + lane * 4); // Wih1 K0..31
    const f16x8 wl1_1 = ldfrag(ws + 12288 + (w * 4 + 1) * 256 + lane * 4); // Wih1 K32..63
    const f16x8 wl1_2 = ldfrag(ws + 12288 + (w * 4 + 2) * 256 + lane * 4); // Whh1 K0..31
    const f16x8 wl1_3 = ldfrag(ws + 12288 + (w * 4 + 3) * 256 + lane * 4); // Whh1 K32..63
    f16x8 wv1 = {}, wv2_0 = {}, wv2_1 = {};
    float4 b1f = {0.f, 0.f, 0.f, 0.f};
    float4 b2f = {0.f, 0.f, 0.f, 0.f};
    const float* wsf = (const float*)ws;
    if (w < 4) {
        wv1 = ldfrag(ws + 28672 + w * 256 + lane * 4);
        b1f = *(const float4*)(wsf + 30208 + (w * 64 + lane) * 4);
    }
    if (w == 4) {
        wv2_0 = ldfrag(ws + 29696 + lane * 4);
        wv2_1 = ldfrag(ws + 29696 + 256 + lane * 4);
        b2f   = *(const float4*)(wsf + 31232 + lane * 4);
    }
    const float4 bias1 = *(const float4*)(wsf + 35584 + (w * 64 + lane) * 4);
    const float woj = Wo[4 * w + q];
    const float bov = bo[0];

    float c0 = 0.f, c1 = 0.f;
    f32x4 a0 = {0.f, 0.f, 0.f, 0.f};    // L0 acc: recurrent part added in P4(t-1)
    float4 px = {0.f, 0.f, 0.f, 0.f};   // x(t+1) prefetch, held by wave 5 lanes 320..351
    __syncthreads();

    // ---- init staging: XS const-1 at k16; XB <- x(0); px <- x(1) ----
    if (tid < 16) *(unsigned short*)(smem + O_XS + (32 + tid) * 16) = 0x3C00;
    if (tid >= 320 && tid < 352) {
        int pb = (tid >> 1) & 15, ph = tid & 1;
        float4 x0 = *(const float4*)(feat + ((size_t)(b0 + pb) * NT) * 8 + 4 * ph);
        uint2 p2; p2.x = pack2(x0.x, x0.y); p2.y = pack2(x0.z, x0.w);
        *(uint2*)(smem + O_XB + pb * 16 + ph * 8) = p2;
        px = *(const float4*)(feat + ((size_t)(b0 + pb) * NT + 1) * 8 + 4 * ph);
    }
    __syncthreads();

    #pragma unroll 1
    for (int t = 0; t < NT; ++t) {
        // ==== P1: L1 recurrent MFMAs (all waves); VSN1 (waves 0-3);
        //          delta(t-1) reg-reduce (waves 0-3 q1, wave 4 q2) ====
        f32x4 a1 = {bias1.x, bias1.y, bias1.z, bias1.w};
        {
            f16x8 h1a = *(const f16x8*)(smem + O_H1 + lane * 16);
            f16x8 h1b = *(const f16x8*)(smem + O_H1 + 1024 + lane * 16);
            a1 = __builtin_amdgcn_mfma_f32_16x16x32_f16(wl1_2, h1a, a1, 0, 0, 0);
            a1 = __builtin_amdgcn_mfma_f32_16x16x32_f16(wl1_3, h1b, a1, 0, 0, 0);
        }
        float dlt = 0.f;   // delta(t-1), valid in (w<4,q1) and (w4,q2) lanes
        if (w < 4) {
            union { uint4 u; f16x8 h; } xbu;
            xbu.u = (uint4){0u, 0u, 0u, 0u};
            if (q == 0) {
                xbu.u = *(const uint4*)(smem + O_XB + cb * 16);
            } else if (q == 1) {
                if (t > 0) dlt = wp_reduce(smem, cb) + bov;
                xbu.u.x = (uint)f16b(dlt);
                if (w == 0 && t > 0) out[(size_t)(b0 + cb) * NT + (t - 1)] = dlt;
            }
            f32x4 acc = {b1f.x, b1f.y, b1f.z, b1f.w};
            acc = __builtin_amdgcn_mfma_f32_16x16x32_f16(wv1, xbu.h, acc, 0, 0, 0);
            uint2 hw;
            hw.x = pack2(fmaxf(acc[0], 0.f), fmaxf(acc[1], 0.f));
            hw.y = pack2(fmaxf(acc[2], 0.f), fmaxf(acc[3], 0.f));
            *(uint2*)(smem + O_HID + ((2 * w + (q >> 1)) * 16 + cb) * 16 + (q & 1) * 8) = hw;
        } else if (w == 4) {
            if (q == 2 && t > 0) dlt = wp_reduce(smem, cb) + bov;
        }
        __syncthreads();   // B

        // ==== P2: VSN2 + softmax (skip-max) + x~ ; wave 4 only ====
        if (w == 4) {
            f16x8 hb0 = *(const f16x8*)(smem + O_HID + lane * 16);
            f16x8 hb1 = *(const f16x8*)(smem + O_HID + 1024 + lane * 16);
            f32x4 acc = {b2f.x, b2f.y, b2f.z, b2f.w};
            acc = __builtin_amdgcn_mfma_f32_16x16x32_f16(wv2_0, hb0, acc, 0, 0, 0);
            acc = __builtin_amdgcn_mfma_f32_16x16x32_f16(wv2_1, hb1, acc, 0, 0, 0);
            float e0 = fexp2(1.44269504f * acc[0]);
            float e1 = fexp2(1.44269504f * acc[1]);
            float e2 = fexp2(1.44269504f * acc[2]);
            float e3 = fexp2(1.44269504f * acc[3]);
            float sm = (e0 + e1) + (e2 + e3);
            sm += __shfl_xor(sm, 16, 64);
            sm += __shfl_xor(sm, 32, 64);
            float inv = frcp(sm);
            float x0 = 0.f, x1 = 0.f, x2 = 0.f, x3 = 0.f;
            if (q < 2) {
                uint2 xw = *(const uint2*)(smem + O_XB + cb * 16 + q * 8);
                const __half* xh = (const __half*)&xw;
                x0 = __half2float(xh[0]); x1 = __half2float(xh[1]);
                x2 = __half2float(xh[2]); x3 = __half2float(xh[3]);
            } else if (q == 2) {
                x0 = dlt;               // k=8 = prev delta
            }
            uint2 xsw;
            xsw.x = pack2(x0 * e0 * inv, x1 * e1 * inv);
            xsw.y = pack2(x2 * e2 * inv, x3 * e3 * inv);
            *(uint2*)(smem + O_XS + ((q >> 1) * 16 + cb) * 16 + (q & 1) * 8) = xsw;
        }
        __syncthreads();   // C

        // ==== P3: LSTM0 finish: 1 MFMA (x~ + fused bias0) + gates ====
        {
            f16x8 bx = *(const f16x8*)(smem + O_XS + lane * 16);
            a0 = __builtin_amdgcn_mfma_f32_16x16x32_f16(wl0_0, bx, a0, 0, 0, 0);
            float h0v = lstm_out(a0, c0);
            *(unsigned short*)(smem + O_H0 + (w >> 1) * 256 + cb * 16 + (4 * (w & 1) + q) * 2) = f16b(h0v);
        }
        __syncthreads();   // D

        // ==== P4: LSTM1 finish (2 MFMA) + next-step L0 recurrent (2 MFMA,
        //          reusing h0 frags) + gates + delta partial + x(t+1) stage ====
        {
            f16x8 h0a = *(const f16x8*)(smem + O_H0 + lane * 16);
            f16x8 h0b = *(const f16x8*)(smem + O_H0 + 1024 + lane * 16);
            a1 = __builtin_amdgcn_mfma_f32_16x16x32_f16(wl1_0, h0a, a1, 0, 0, 0);
            a1 = __builtin_amdgcn_mfma_f32_16x16x32_f16(wl1_1, h0b, a1, 0, 0, 0);
            f32x4 a0n = {0.f, 0.f, 0.f, 0.f};
            a0n = __builtin_amdgcn_mfma_f32_16x16x32_f16(wl0_1, h0a, a0n, 0, 0, 0);
            a0n = __builtin_amdgcn_mfma_f32_16x16x32_f16(wl0_2, h0b, a0n, 0, 0, 0);
            a0 = a0n;
            float h1v = lstm_out(a1, c1);
            *(unsigned short*)(smem + O_H1 + (w >> 1) * 256 + cb * 16 + (4 * (w & 1) + q) * 2) = f16b(h1v);
            float p = woj * h1v;
            p += __shfl_xor(p, 16, 64);
            p += __shfl_xor(p, 32, 64);
            if (q == 0) ((float*)(smem + O_WP))[cb * 20 + w] = p;
        }
        if (tid >= 320 && tid < 352) {   // wave 5: stage x(t+1), prefetch x(t+2)
            int pb = (tid >> 1) & 15, ph = tid & 1;
            uint2 p2; p2.x = pack2(px.x, px.y); p2.y = pack2(px.z, px.w);
            *(uint2*)(smem + O_XB + pb * 16 + ph * 8) = p2;
            if (t + 2 < NT)
                px = *(const float4*)(feat + ((size_t)(b0 + pb) * NT + (t + 2)) * 8 + 4 * ph);
        }
        __syncthreads();   // E
    }

    // ---- epilogue: delta for t = 255 ----
    if (tid < 16) {
        float s = wp_reduce(smem, tid) + bov;
        out[(size_t)(b0 + tid) * NT + (NT - 1)] = s;
    }
}

extern "C" void kernel_launch(void* const* d_in, const int* in_sizes, int n_in,
                              void* d_out, int out_size, void* d_ws, size_t ws_size,
                              hipStream_t stream) {
    const float* feat = (const float*)d_in[0];
    const float* W1   = (const float*)d_in[1];
    const float* b1   = (const float*)d_in[2];
    const float* W2   = (const float*)d_in[3];
    const float* b2   = (const float*)d_in[4];
    const float* Wih0 = (const float*)d_in[5];
    const float* Whh0 = (const float*)d_in[6];
    const float* bih0 = (const float*)d_in[7];
    const float* bhh0 = (const float*)d_in[8];
    const float* Wih1 = (const float*)d_in[9];
    const float* Whh1 = (const float*)d_in[10];
    const float* bih1 = (const float*)d_in[11];
    const float* bhh1 = (const float*)d_in[12];
    const float* Wo   = (const float*)d_in[13];
    const float* bo   = (const float*)d_in[14];
    uint* ws   = (uint*)d_ws;
    float* out = (float*)d_out;

    hipLaunchKernelGGL(prep_kernel, dim3(40), dim3(1024), 0, stream,
                       W1, b1, W2, b2, Wih0, Whh0, bih0, bhh0,
                       Wih1, Whh1, bih1, bhh1, ws);
    // 256 blocks x 1024 threads: 16 batches/block, 1 block/CU
    hipLaunchKernelGGL(tft_main, dim3(256), dim3(1024), 0, stream,
                       feat, Wo, bo, ws, out);
}